// Round 2
// baseline (397.396 us; speedup 1.0000x reference)
//
#include <hip/hip_runtime.h>
#include <stdint.h>

// ws layout (float offsets)
#define WS_HMUE 0          // [16][64][256] h_mean_ue (mean over p2 = row sums)
#define WS_HMAP 262144     // [16][64][256] h_mean_ap (mean over p1 = col sums)
#define WS_APM  524288     // [16][64] ap_mean
#define WS_UEM  525312     // [16][64] ue_mean
#define WS_Z    526336     // [2][16][64][256] pre-BN z (fp32), 524288 floats

// Kernel 1: H both-axis means + A row means.
// Blocks 0..1023: one (b,d2) slice of H (256x256 fp32 = 256KB).
// Blocks 1024..1535: A_AP/A_UE row means (4 rows/block, one row per wave).
__global__ __launch_bounds__(256) void k_reduce(
    const float* __restrict__ H,
    const float* __restrict__ A_AP, const float* __restrict__ A_UE,
    float* __restrict__ ws)
{
    const int bid = blockIdx.x;
    const int tid = threadIdx.x;
    const int w = tid >> 6;       // wave 0..3
    const int lane = tid & 63;

    __shared__ float lds_row[256];
    __shared__ float lds_col[1024];   // [4 waves][256 cols]

    if (bid < 1024) {
        // slice rows = p1, cols = p2; row-major, row stride 256 floats
        const float4* Hs = (const float4*)(H + (size_t)bid * 65536);
        float c0 = 0.f, c1 = 0.f, c2 = 0.f, c3 = 0.f;

        #pragma unroll 8
        for (int it = 0; it < 64; ++it) {
            const int row = it * 4 + w;
            float4 v = Hs[row * 64 + lane];   // lane covers cols 4*lane..4*lane+3
            c0 += v.x; c1 += v.y; c2 += v.z; c3 += v.w;
            float rs = (v.x + v.y) + (v.z + v.w);
            rs += __shfl_xor(rs, 1);
            rs += __shfl_xor(rs, 2);
            rs += __shfl_xor(rs, 4);
            rs += __shfl_xor(rs, 8);
            rs += __shfl_xor(rs, 16);
            rs += __shfl_xor(rs, 32);
            if (lane == 0) lds_row[row] = rs;
        }
        ((float4*)lds_col)[w * 64 + lane] = make_float4(c0, c1, c2, c3);
        __syncthreads();
        const float cs = lds_col[tid] + lds_col[256 + tid]
                       + lds_col[512 + tid] + lds_col[768 + tid];
        const int oidx = bid * 256 + tid;
        ws[WS_HMAP + oidx] = cs * (1.f / 256.f);           // mean over p1 (rows)
        ws[WS_HMUE + oidx] = lds_row[tid] * (1.f / 256.f); // mean over p2 (cols)
    } else {
        const int m = bid - 1024;     // 0..511
        const int r = m * 4 + w;      // 0..2047: 0..1023 = A_AP, 1024..2047 = A_UE
        const bool is_ap = (r < 1024);
        const float4* src = is_ap ? (const float4*)(A_AP + r * 256)
                                  : (const float4*)(A_UE + (r - 1024) * 256);
        float4 v = src[lane];
        float s = (v.x + v.y) + (v.z + v.w);
        s += __shfl_xor(s, 1);
        s += __shfl_xor(s, 2);
        s += __shfl_xor(s, 4);
        s += __shfl_xor(s, 8);
        s += __shfl_xor(s, 16);
        s += __shfl_xor(s, 32);
        if (lane == 0) {
            if (is_ap) ws[WS_APM + r] = s * (1.f / 256.f);
            else       ws[WS_UEM + (r - 1024)] = s * (1.f / 256.f);
        }
    }
}

// Kernel 2: z[g][b][o][p] = relu( 2*(sum_d Q1[o,d]A[b,d,p] + s2[b,o]) + 0.1*sum_d P1[o,d]hm[b,d,p] )
// block = (g, b, o-tile of 4); thread = p.
__global__ __launch_bounds__(256) void k_z(
    const float* __restrict__ A_AP, const float* __restrict__ A_UE,
    const float* __restrict__ Q1_AP, const float* __restrict__ Q2_AP,
    const float* __restrict__ Q1_UE, const float* __restrict__ Q2_UE,
    const float* __restrict__ P1_AP, const float* __restrict__ P1_UE,
    const float* __restrict__ hmue, const float* __restrict__ hmap,
    const float* __restrict__ apm,  const float* __restrict__ uem,
    float* __restrict__ z)
{
    const int bid = blockIdx.x;
    const int g = bid >> 8;
    const int rem = bid & 255;
    const int b = rem >> 4;
    const int o0 = (rem & 15) * 4;
    const int p = threadIdx.x;

    const float* A  = g ? A_UE : A_AP;
    const float* hm = g ? hmap : hmue;
    const float* am = g ? apm  : uem;   // out_ap uses ue_mean; out_ue uses ap_mean
    const float* Q1 = g ? Q1_UE : Q1_AP;
    const float* Q2 = g ? Q2_UE : Q2_AP;
    const float* P1 = g ? P1_UE : P1_AP;

    __shared__ float s2[4];
    if (threadIdx.x < 4) {
        const float* qr = Q2 + (o0 + threadIdx.x) * 64;
        const float* ar = am + b * 64;
        float s = 0.f;
        #pragma unroll
        for (int d = 0; d < 64; ++d) s += qr[d] * ar[d];
        s2[threadIdx.x] = s;
    }
    __syncthreads();

    float accQ[4] = {0.f, 0.f, 0.f, 0.f};
    float accP[4] = {0.f, 0.f, 0.f, 0.f};
    const float* Ab = A  + (b << 14) + p;   // b*64*256
    const float* hb = hm + (b << 14) + p;

    #pragma unroll 4
    for (int dd = 0; dd < 16; ++dd) {
        const int d0 = dd * 4;
        float a0 = Ab[(d0 + 0) * 256];
        float a1 = Ab[(d0 + 1) * 256];
        float a2 = Ab[(d0 + 2) * 256];
        float a3 = Ab[(d0 + 3) * 256];
        float h0 = hb[(d0 + 0) * 256];
        float h1 = hb[(d0 + 1) * 256];
        float h2 = hb[(d0 + 2) * 256];
        float h3 = hb[(d0 + 3) * 256];
        #pragma unroll
        for (int j = 0; j < 4; ++j) {
            const float4 q  = *(const float4*)(Q1 + (o0 + j) * 64 + d0);
            const float4 pc = *(const float4*)(P1 + (o0 + j) * 64 + d0);
            accQ[j] += q.x * a0 + q.y * a1 + q.z * a2 + q.w * a3;
            accP[j] += pc.x * h0 + pc.y * h1 + pc.z * h2 + pc.w * h3;
        }
    }

    #pragma unroll
    for (int j = 0; j < 4; ++j) {
        float zv = 2.f * (accQ[j] + s2[j]) + 0.1f * accP[j];
        zv = fmaxf(zv, 0.f);
        z[((size_t)(g * 16 + b) * 64 + (o0 + j)) * 256 + p] = zv;
    }
}

// Kernel 3: BatchNorm train-mode per channel o over (b,p): 4096 elems in registers.
__global__ __launch_bounds__(256) void k_bn(
    const float* __restrict__ z,
    const float* __restrict__ gamma, const float* __restrict__ beta,
    float* __restrict__ out)
{
    const int g = blockIdx.x >> 6;
    const int o = blockIdx.x & 63;
    const int t = threadIdx.x;
    const int w = t >> 6;
    const int lane = t & 63;

    const float* zp = z + (size_t)g * 262144 + o * 256 + t;  // b stride = 16384
    float v[16];
    float s = 0.f, q = 0.f;
    #pragma unroll
    for (int b = 0; b < 16; ++b) {
        float x = zp[b * 16384];
        v[b] = x;
        s += x;
        q += x * x;
    }
    #pragma unroll
    for (int m = 1; m <= 32; m <<= 1) {
        s += __shfl_xor(s, m);
        q += __shfl_xor(q, m);
    }
    __shared__ float ls[4], lq[4];
    if (lane == 0) { ls[w] = s; lq[w] = q; }
    __syncthreads();
    s = ls[0] + ls[1] + ls[2] + ls[3];
    q = lq[0] + lq[1] + lq[2] + lq[3];

    const float mean = s * (1.f / 4096.f);
    const float var  = q * (1.f / 4096.f) - mean * mean;
    const float rstd = rsqrtf(var + 1e-5f);
    const float scale = rstd * gamma[o];
    const float shift = beta[o] - mean * scale;

    float* op = out + (size_t)g * 262144 + o * 256 + t;
    #pragma unroll
    for (int b = 0; b < 16; ++b)
        op[b * 16384] = v[b] * scale + shift;
}

extern "C" void kernel_launch(void* const* d_in, const int* in_sizes, int n_in,
                              void* d_out, int out_size, void* d_ws, size_t ws_size,
                              hipStream_t stream)
{
    const float* A_AP  = (const float*)d_in[0];
    const float* A_UE  = (const float*)d_in[1];
    const float* H     = (const float*)d_in[2];
    const float* Q1_AP = (const float*)d_in[3];
    const float* Q2_AP = (const float*)d_in[4];
    const float* Q1_UE = (const float*)d_in[5];
    const float* Q2_UE = (const float*)d_in[6];
    const float* P1_AP = (const float*)d_in[7];
    const float* P1_UE = (const float*)d_in[8];
    const float* gamma = (const float*)d_in[9];
    const float* beta  = (const float*)d_in[10];

    float* ws = (float*)d_ws;
    float* out = (float*)d_out;

    hipLaunchKernelGGL(k_reduce, dim3(1536), dim3(256), 0, stream,
                       H, A_AP, A_UE, ws);

    hipLaunchKernelGGL(k_z, dim3(512), dim3(256), 0, stream,
                       A_AP, A_UE, Q1_AP, Q2_AP, Q1_UE, Q2_UE, P1_AP, P1_UE,
                       ws + WS_HMUE, ws + WS_HMAP, ws + WS_APM, ws + WS_UEM,
                       ws + WS_Z);

    hipLaunchKernelGGL(k_bn, dim3(128), dim3(256), 0, stream,
                       ws + WS_Z, gamma, beta, out);
}